// Round 2
// baseline (203.665 us; speedup 1.0000x reference)
//
#include <hip/hip_runtime.h>
#include <math.h>

#define NUM_GRID 16
#define NCELLS   256          // 16*16 cells per map
#define THRESH   0.65f
#define NUM_FG   40
#define NUM_BG   1
#define MAX_PTS  42
#define T_DIM    8
#define C_DIM    4
#define H_DIM    1024
#define W_DIM    1024
#define NMAPS    (T_DIM * C_DIM)          // 32
#define MAP_ELEMS (H_DIM * W_DIM)         // 1048576
#define CELL_DIM 64                       // 1024/16
#define NSPLIT   4                        // row-splits per cell strip
#define ROWS_PER_SPLIT (CELL_DIM / NSPLIT)  // 16

// Kernel 1: one block per (map, cell-row cy, split s). 256 threads.
// Each thread owns a fixed 4-column stripe (=> fixed cell cx = tid>>4) and
// streams ROWS_PER_SPLIT contiguous rows; block reads one contiguous 4KB row
// per iteration (perfect coalescing). Per-thread (max,argmax)/(min,argmin)
// in increasing flat-index order (strict compares => min-index tie-break),
// then a barrier-free 16-lane shuffle reduction per cell.
__global__ __launch_bounds__(256)
void cell_stats_kernel(const float* __restrict__ sim,
                       float* __restrict__ maxv_o, int* __restrict__ maxi_o,
                       float* __restrict__ minv_o, int* __restrict__ mini_o) {
    const int b   = blockIdx.x;            // 0..NMAPS*16*NSPLIT-1
    const int map = b >> 6;
    const int cy  = (b >> 2) & 15;
    const int s   = b & 3;
    const int tid = threadIdx.x;           // 0..255; col = 4*tid

    const int row0 = cy * CELL_DIM + s * ROWS_PER_SPLIT;
    const float* __restrict__ p =
        sim + (size_t)map * MAP_ELEMS + (size_t)row0 * W_DIM + tid * 4;
    int ix0 = row0 * W_DIM + tid * 4;

    float mxv = -INFINITY; int mxi = 0x7fffffff;
    float mnv =  INFINITY; int mni = 0x7fffffff;

    #pragma unroll 4
    for (int r = 0; r < ROWS_PER_SPLIT; ++r) {
        const float4 v4 = *reinterpret_cast<const float4*>(p);
        const float vals[4] = {v4.x, v4.y, v4.z, v4.w};
        #pragma unroll
        for (int j = 0; j < 4; ++j) {
            const float v  = vals[j];
            const int   ix = ix0 + j;
            if (v > mxv) { mxv = v; mxi = ix; }   // strict > keeps min idx
            if (v < mnv) { mnv = v; mni = ix; }
        }
        p   += W_DIM;
        ix0 += W_DIM;
    }

    // reduce within 16-lane groups (one group per cell); min-idx tie-break
    #pragma unroll
    for (int mask = 1; mask <= 8; mask <<= 1) {
        float ov = __shfl_xor(mxv, mask, 64);
        int   oi = __shfl_xor(mxi, mask, 64);
        if (ov > mxv || (ov == mxv && oi < mxi)) { mxv = ov; mxi = oi; }
        float uv = __shfl_xor(mnv, mask, 64);
        int   ui = __shfl_xor(mni, mask, 64);
        if (uv < mnv || (uv == mnv && ui < mni)) { mnv = uv; mni = ui; }
    }

    if ((tid & 15) == 0) {
        const int cx = tid >> 4;
        const int o  = ((map * NCELLS + cy * NUM_GRID + cx) * NSPLIT) + s;
        maxv_o[o] = mxv; maxi_o[o] = mxi;
        minv_o[o] = mnv; mini_o[o] = mni;
    }
}

// (value, index) block reduction over 256 threads.
__device__ inline void block_reduce_pair(float& v, int& i, bool is_max,
                                         float* sv, int* si, int tid) {
    sv[tid] = v; si[tid] = i;
    __syncthreads();
    for (int s = 128; s > 0; s >>= 1) {
        if (tid < s) {
            float v2 = sv[tid + s]; int i2 = si[tid + s];
            float v1 = sv[tid];     int i1 = si[tid];
            bool take = is_max ? (v2 > v1 || (v2 == v1 && i2 < i1))
                               : (v2 < v1 || (v2 == v1 && i2 < i1));
            if (take) { sv[tid] = v2; si[tid] = i2; }
        }
        __syncthreads();
    }
    v = sv[0]; i = si[0];
    __syncthreads();   // safe reuse of sv/si afterwards
}

// Kernel 2: one block per map, 256 threads = one per cell.
// Merge NSPLIT partials, derive fg from cell max, global max/min reductions,
// stable descending rank, emit rows.
__global__ __launch_bounds__(256)
void select_kernel(const float* __restrict__ maxv_i, const int* __restrict__ maxi_i,
                   const float* __restrict__ minv_i, const int* __restrict__ mini_i,
                   const int* __restrict__ orig_sizes,
                   float* __restrict__ out_pts, float* __restrict__ out_nums) {
    const int m   = blockIdx.x;    // 0..31
    const int tid = threadIdx.x;   // cell id
    const int t   = m >> 2;        // map = t*C + c

    const float sx = (float)orig_sizes[t * 2 + 1] / (float)W_DIM;
    const float sy = (float)orig_sizes[t * 2 + 0] / (float)H_DIM;

    // merge split partials for this cell (splits cover increasing indices;
    // explicit tie-break anyway)
    float mxv = -INFINITY; int mxi = 0x7fffffff;
    float mnv =  INFINITY; int mni = 0x7fffffff;
    const int base = (m * NCELLS + tid) * NSPLIT;
    #pragma unroll
    for (int s = 0; s < NSPLIT; ++s) {
        const float ov = maxv_i[base + s]; const int oi = maxi_i[base + s];
        if (ov > mxv || (ov == mxv && oi < mxi)) { mxv = ov; mxi = oi; }
        const float uv = minv_i[base + s]; const int ui = mini_i[base + s];
        if (uv < mnv || (uv == mnv && ui < mni)) { mnv = uv; mni = ui; }
    }

    // fg-masked cell max == overall cell max when > THRESH (and same argmax)
    const bool  valid = (mxv > THRESH);
    const float fgv   = valid ? mxv : -INFINITY;
    const int   fgi   = mxi;

    __shared__ float skey[256];
    skey[tid] = fgv;

    __shared__ float sv[256];
    __shared__ int   si[256];

    // global (unmasked) argmax  -> jnp.argmax fallback
    float gv = mxv; int gi = mxi;
    block_reduce_pair(gv, gi, true, sv, si, tid);
    // global argmin             -> top_k(-flat, 1)
    float bv = mnv; int bi = mni;
    block_reduce_pair(bv, bi, false, sv, si, tid);

    const int nvalid = __syncthreads_count(valid ? 1 : 0);
    const bool any_fg = (nvalid > 0);
    const int fg_count = any_fg ? (nvalid < NUM_FG ? nvalid : NUM_FG) : 1;

    // stable descending rank: #{j : key_j > key_i or (key_j == key_i and j < i)}
    int rank = 0;
    const float key = fgv;
    for (int j = 0; j < 256; ++j) {
        const float kj = skey[j];
        rank += (kj > key || (kj == key && j < tid)) ? 1 : 0;
    }

    __shared__ float outp[MAX_PTS * 4];
    if (tid < MAX_PTS * 4) outp[tid] = 0.0f;
    __syncthreads();

    if (any_fg && valid && rank < NUM_FG) {
        const int col = fgi & (W_DIM - 1);
        const int row = fgi >> 10;
        outp[rank * 4 + 0] = (float)col * sx;
        outp[rank * 4 + 1] = (float)row * sy;
        outp[rank * 4 + 2] = fgv;
        outp[rank * 4 + 3] = 1.0f;
    }
    if (!any_fg && tid == 0) {
        const int col = gi & (W_DIM - 1);
        const int row = gi >> 10;
        outp[0] = (float)col * sx;
        outp[1] = (float)row * sy;
        outp[2] = gv;
        outp[3] = 1.0f;
    }
    __syncthreads();

    if (tid == 0) {
        const int col = bi & (W_DIM - 1);
        const int row = bi >> 10;
        outp[fg_count * 4 + 0] = (float)col * sx;
        outp[fg_count * 4 + 1] = (float)row * sy;
        outp[fg_count * 4 + 2] = bv;
        outp[fg_count * 4 + 3] = 0.0f;
    }
    __syncthreads();

    if (tid < MAX_PTS * 4) out_pts[(size_t)m * (MAX_PTS * 4) + tid] = outp[tid];
    if (tid == 0) out_nums[m] = (float)(fg_count + NUM_BG);
}

extern "C" void kernel_launch(void* const* d_in, const int* in_sizes, int n_in,
                              void* d_out, int out_size, void* d_ws, size_t ws_size,
                              hipStream_t stream) {
    const float* sim        = (const float*)d_in[0];
    // d_in[1] = category_ids (unused by forward)
    const int*   orig_sizes = (const int*)d_in[2];

    float* out = (float*)d_out;
    float* out_pts  = out;                                   // (T,C,42,4) = 5376 floats
    float* out_nums = out + (size_t)NMAPS * MAX_PTS * 4;     // (T,C)      = 32 floats

    // workspace: 32 maps * 256 cells * NSPLIT partials, SoA
    const size_t NP = (size_t)NMAPS * NCELLS * NSPLIT;       // 32768
    char* ws = (char*)d_ws;
    float* maxv_ws = (float*)(ws + 0 * NP * 4);
    int*   maxi_ws = (int*)  (ws + 1 * NP * 4);
    float* minv_ws = (float*)(ws + 2 * NP * 4);
    int*   mini_ws = (int*)  (ws + 3 * NP * 4);

    cell_stats_kernel<<<NMAPS * NUM_GRID * NSPLIT, 256, 0, stream>>>(
        sim, maxv_ws, maxi_ws, minv_ws, mini_ws);

    select_kernel<<<NMAPS, 256, 0, stream>>>(
        maxv_ws, maxi_ws, minv_ws, mini_ws,
        orig_sizes, out_pts, out_nums);
}